// Round 3
// baseline (135.865 us; speedup 1.0000x reference)
//
#include <hip/hip_runtime.h>

#define ROWS 4096
#define COLS 2048
#define NLEV 16
#define TEMP 100.0f
#define EPS  1e-6f
#define LOG2E 1.4426950408889634f

#define TPB 256            // threads per block = columns per block
#define UNROLL 8

// d_ws layout: float partial[RBLKS][COLS][NLEV]; RBLKS chosen from ws_size.

template <int RPB>
__global__ __launch_bounds__(TPB) void quant_main_kernel(
    const float* __restrict__ weight,
    const float* __restrict__ w_min,
    const float* __restrict__ w_max,
    float* __restrict__ dequant,
    float* __restrict__ partial)
{
    const int c  = blockIdx.x * TPB + threadIdx.x;   // column (coalesced)
    const int r0 = blockIdx.y * RPB;

    const float wmin = w_min[c];
    const float wmax = w_max[c];
    const float mn   = fminf(wmin, wmax - EPS);       // w_min_c
    const float mx   = fmaxf(wmax, mn + EPS);         // w_max_c
    const float rng  = mx - mn;
    const float inv_rng = __builtin_amdgcn_rcpf(rng + EPS);

    // exp(-T*|x - l/15|) == exp2(-|z - l*STEP|), z = x*T*log2e
    const float scale = inv_rng * (TEMP * LOG2E);
    const float STEP  = (TEMP / 15.0f) * LOG2E;
    const float rng15 = rng * (1.0f / 15.0f);

    float acc[NLEV];
#pragma unroll
    for (int l = 0; l < NLEV; ++l) acc[l] = 0.0f;

    const float* __restrict__ wp = weight  + (size_t)r0 * COLS + c;
    float* __restrict__       dq = dequant + (size_t)r0 * COLS + c;

    for (int r = 0; r < RPB; r += UNROLL) {
        float w[UNROLL];
#pragma unroll
        for (int j = 0; j < UNROLL; ++j)
            w[j] = wp[(size_t)(r + j) * COLS];

#pragma unroll
        for (int j = 0; j < UNROLL; ++j) {
            const float z = (w[j] - mn) * scale;

            float p[NLEV];
            float s  = 0.0f;
            float ws = 0.0f;
#pragma unroll
            for (int l = 0; l < NLEV; ++l) {
                const float d = z - (float)l * STEP;
                const float e = __builtin_amdgcn_exp2f(-fabsf(d));
                p[l] = e;
                s   += e;
                ws  += e * (float)l;
            }
            const float inv_s = __builtin_amdgcn_rcpf(s);
            dq[(size_t)(r + j) * COLS] = ws * inv_s * rng15 + mn;
#pragma unroll
            for (int l = 0; l < NLEV; ++l) acc[l] += p[l] * inv_s;
        }
    }

    float4* pp = (float4*)(partial + ((size_t)blockIdx.y * COLS + c) * NLEV);
#pragma unroll
    for (int q = 0; q < NLEV / 4; ++q)
        pp[q] = make_float4(acc[q*4], acc[q*4+1], acc[q*4+2], acc[q*4+3]);
}

// 4 threads per column, each owns one float4 of levels. 32 blocks x 256.
__global__ __launch_bounds__(256) void entropy_kernel(
    const float* __restrict__ partial,
    float* __restrict__ out_ent,
    int rblks)
{
    __shared__ float red[256];
    const int t    = blockIdx.x * 256 + threadIdx.x;
    const int col  = t >> 2;
    const int quad = t & 3;

    float4 m = make_float4(0.f, 0.f, 0.f, 0.f);
    for (int rb = 0; rb < rblks; ++rb) {
        const float4 v = *(const float4*)(partial +
            ((size_t)rb * COLS + col) * NLEV + quad * 4);
        m.x += v.x; m.y += v.y; m.z += v.z; m.w += v.w;
    }

    float tot = m.x + m.y + m.z + m.w;
    tot += __shfl_xor(tot, 1);
    tot += __shfl_xor(tot, 2);          // all 4 lanes of the quad: column total
    const float inv = __builtin_amdgcn_rcpf(tot + EPS);

    float ent = 0.0f;
    {
        const float p0 = m.x * inv, p1 = m.y * inv, p2 = m.z * inv, p3 = m.w * inv;
        ent -= p0 * __logf(p0 + EPS);
        ent -= p1 * __logf(p1 + EPS);
        ent -= p2 * __logf(p2 + EPS);
        ent -= p3 * __logf(p3 + EPS);
    }

    red[threadIdx.x] = ent;
    __syncthreads();
#pragma unroll
    for (int off = 128; off > 0; off >>= 1) {
        if (threadIdx.x < off) red[threadIdx.x] += red[threadIdx.x + off];
        __syncthreads();
    }
    if (threadIdx.x == 0) atomicAdd(out_ent, red[0]);   // 32 atomics total
}

extern "C" void kernel_launch(void* const* d_in, const int* in_sizes, int n_in,
                              void* d_out, int out_size, void* d_ws, size_t ws_size,
                              hipStream_t stream)
{
    const float* weight = (const float*)d_in[0];
    const float* w_min  = (const float*)d_in[1];
    const float* w_max  = (const float*)d_in[2];

    float* out     = (float*)d_out;
    float* dequant = out;                          // ROWS*COLS floats
    float* out_ent = out + (size_t)ROWS * COLS;    // 1 float
    float* partial = (float*)d_ws;

    hipMemsetAsync(out_ent, 0, sizeof(float), stream);

    const size_t per_rblk = (size_t)COLS * NLEV * sizeof(float);
    int rblks;
    if (ws_size >= 128 * per_rblk) {
        rblks = 128;
        quant_main_kernel<32><<<dim3(COLS / TPB, 128), TPB, 0, stream>>>(
            weight, w_min, w_max, dequant, partial);
    } else if (ws_size >= 64 * per_rblk) {
        rblks = 64;
        quant_main_kernel<64><<<dim3(COLS / TPB, 64), TPB, 0, stream>>>(
            weight, w_min, w_max, dequant, partial);
    } else {
        rblks = 32;
        quant_main_kernel<128><<<dim3(COLS / TPB, 32), TPB, 0, stream>>>(
            weight, w_min, w_max, dequant, partial);
    }

    entropy_kernel<<<(COLS * 4) / 256, 256, 0, stream>>>(partial, out_ent, rblks);
}

// Round 4
// 108.357 us; speedup vs baseline: 1.2539x; 1.2539x over previous
//
#include <hip/hip_runtime.h>

#define ROWS 4096
#define COLS 2048
#define NLEV 16
#define TEMP 100.0f
#define EPS  1e-6f
#define LOG2E 1.4426950408889634f

#define TPB 256            // threads per block = columns per block
#define RPB 32             // rows per block
#define RBLKS (ROWS / RPB) // 128 row-blocks
#define UNROLL 8

// geometric ratio between adjacent levels: exp(-T/15) = exp(-6.6667)
#define RGEO 1.2726356e-3f

// d_ws: float partial[RBLKS][COLS][NLEV] (16.8 MB) then float reduced[COLS][NLEV]

__global__ __launch_bounds__(TPB) void quant_main_kernel(
    const float* __restrict__ weight,
    const float* __restrict__ w_min,
    const float* __restrict__ w_max,
    float* __restrict__ dequant,
    float* __restrict__ partial)
{
    // per-thread bins, 18 rows: row = level+1, rows 0 and 17 are dummies that
    // absorb the (coefficient==0) writes at clamped k=0 / k=14.
    // addr = row*TPB + t  -> bank = t mod 32 independent of row: 2-way, free.
    __shared__ float bins[18 * TPB];

    const int t  = threadIdx.x;
    const int c  = blockIdx.x * TPB + t;     // column (coalesced)
    const int r0 = blockIdx.y * RPB;

#pragma unroll
    for (int l = 0; l < 18; ++l) bins[l * TPB + t] = 0.0f;
    // no __syncthreads needed: each thread only ever touches bins[*][t]

    const float wmin = w_min[c];
    const float wmax = w_max[c];
    const float mn   = fminf(wmin, wmax - EPS);       // w_min_c
    const float mx   = fmaxf(wmax, mn + EPS);         // w_max_c
    const float rng  = mx - mn;
    const float inv_rng = __builtin_amdgcn_rcpf(rng + EPS);

    const float S     = (TEMP / 15.0f) * LOG2E;       // level spacing in exp2 units
    const float invS  = 15.0f / (TEMP * LOG2E);
    const float scale = inv_rng * (TEMP * LOG2E);     // z = (w-mn)*scale
    const float rng15 = rng * (1.0f / 15.0f);

    const float* __restrict__ wp = weight  + (size_t)r0 * COLS + c;
    float* __restrict__       dq = dequant + (size_t)r0 * COLS + c;

    for (int r = 0; r < RPB; r += UNROLL) {
        float w[UNROLL];
#pragma unroll
        for (int j = 0; j < UNROLL; ++j)
            w[j] = wp[(size_t)(r + j) * COLS];

#pragma unroll
        for (int j = 0; j < UNROLL; ++j) {
            const float z  = (w[j] - mn) * scale;
            float kf = floorf(z * invS);
            kf = fminf(fmaxf(kf, 0.0f), 14.0f);       // med3; z in (0,15S) by construction
            const int ki = (int)kf;
            const float f = z - kf * S;               // in [0,S)

            // softmax truncated to levels {k-1,k,k+1,k+2}; dropped terms <= r^2 ~ 1.6e-6 rel
            const float t_ = __builtin_amdgcn_exp2f(-fabsf(f));        // e_k
            const float u_ = __builtin_amdgcn_exp2f(-fabsf(f - S));    // e_{k+1}
            const float tl = t_ * ((kf >= 1.0f)  ? RGEO : 0.0f);       // e_{k-1}
            const float uh = u_ * ((kf <= 13.0f) ? RGEO : 0.0f);       // e_{k+2}

            const float s     = t_ + u_ + tl + uh;
            const float inv_s = __builtin_amdgcn_rcpf(s);
            // ws = t*k + u*(k+1) + tl*(k-1) + uh*(k+2) = k*s + (u - tl + 2*uh)
            const float ws = kf * s + (u_ - tl + 2.0f * uh);

            dq[(size_t)(r + j) * COLS] = ws * inv_s * rng15 + mn;

            const int base = ki * TPB + t;            // row for l=k-1 is (k-1)+1 = k
            bins[base          ] += tl * inv_s;
            bins[base + 1 * TPB] += t_ * inv_s;
            bins[base + 2 * TPB] += u_ * inv_s;
            bins[base + 3 * TPB] += uh * inv_s;
        }
    }

    // flush per-thread bins (rows 1..16 = levels 0..15) to global partials
    float4* pp = (float4*)(partial + ((size_t)blockIdx.y * COLS + c) * NLEV);
#pragma unroll
    for (int q = 0; q < NLEV / 4; ++q) {
        pp[q] = make_float4(bins[(q * 4 + 1) * TPB + t],
                            bins[(q * 4 + 2) * TPB + t],
                            bins[(q * 4 + 3) * TPB + t],
                            bins[(q * 4 + 4) * TPB + t]);
    }
}

// stage 1: reduce partial over RBLKS. one thread per (col,level): 32768 threads.
__global__ __launch_bounds__(256) void reduce_kernel(
    const float* __restrict__ partial,
    float* __restrict__ reduced)
{
    const int i = blockIdx.x * 256 + threadIdx.x;    // [0, COLS*NLEV)
    float s = 0.0f;
#pragma unroll 4
    for (int rb = 0; rb < RBLKS; ++rb)
        s += partial[(size_t)rb * (COLS * NLEV) + i];
    reduced[i] = s;
}

// stage 2: entropy. 4 threads per column. 32 blocks x 256.
__global__ __launch_bounds__(256) void entropy_kernel(
    const float* __restrict__ reduced,
    float* __restrict__ out_ent)
{
    __shared__ float red[256];
    const int t    = blockIdx.x * 256 + threadIdx.x;
    const int col  = t >> 2;
    const int quad = t & 3;

    const float4 m = *(const float4*)(reduced + (size_t)col * NLEV + quad * 4);

    float tot = m.x + m.y + m.z + m.w;
    tot += __shfl_xor(tot, 1);
    tot += __shfl_xor(tot, 2);          // column total across the quad
    const float inv = __builtin_amdgcn_rcpf(tot + EPS);

    float ent = 0.0f;
    {
        const float p0 = m.x * inv, p1 = m.y * inv, p2 = m.z * inv, p3 = m.w * inv;
        ent -= p0 * __logf(p0 + EPS);
        ent -= p1 * __logf(p1 + EPS);
        ent -= p2 * __logf(p2 + EPS);
        ent -= p3 * __logf(p3 + EPS);
    }

    red[threadIdx.x] = ent;
    __syncthreads();
#pragma unroll
    for (int off = 128; off > 0; off >>= 1) {
        if (threadIdx.x < off) red[threadIdx.x] += red[threadIdx.x + off];
        __syncthreads();
    }
    if (threadIdx.x == 0) atomicAdd(out_ent, red[0]);   // 32 atomics total
}

extern "C" void kernel_launch(void* const* d_in, const int* in_sizes, int n_in,
                              void* d_out, int out_size, void* d_ws, size_t ws_size,
                              hipStream_t stream)
{
    const float* weight = (const float*)d_in[0];
    const float* w_min  = (const float*)d_in[1];
    const float* w_max  = (const float*)d_in[2];

    float* out     = (float*)d_out;
    float* dequant = out;                          // ROWS*COLS floats
    float* out_ent = out + (size_t)ROWS * COLS;    // 1 float
    float* partial = (float*)d_ws;                 // RBLKS*COLS*NLEV floats
    float* reduced = partial + (size_t)RBLKS * COLS * NLEV;  // COLS*NLEV floats

    hipMemsetAsync(out_ent, 0, sizeof(float), stream);

    quant_main_kernel<<<dim3(COLS / TPB, RBLKS), TPB, 0, stream>>>(
        weight, w_min, w_max, dequant, partial);

    reduce_kernel<<<(COLS * NLEV) / 256, 256, 0, stream>>>(partial, reduced);

    entropy_kernel<<<(COLS * 4) / 256, 256, 0, stream>>>(reduced, out_ent);
}

// Round 5
// 100.182 us; speedup vs baseline: 1.3562x; 1.0816x over previous
//
#include <hip/hip_runtime.h>

#define ROWS 4096
#define COLS 2048
#define NLEV 16
#define TEMP 100.0f
#define EPS  1e-6f
#define LOG2E 1.4426950408889634f
// geometric ratio between adjacent levels: exp(-100/15)
#define RGEO 1.2726356e-3f

#define TPB 128            // threads per block = columns per block
#define RPB 32             // rows per block
#define RBLKS (ROWS / RPB) // 128 row-blocks
#define UNROLL 8

typedef _Float16 half8_t __attribute__((ext_vector_type(8)));
typedef _Float16 half2_t __attribute__((ext_vector_type(2)));

// d_ws: _Float16 partial[RBLKS][COLS][NLEV]  = 8.4 MB
//
// Gather factorization: per element only A[k] += t*inv_s, B[k] += u*inv_s.
// bin[l] = A[l] + B[l-1] + RGEO*(A[l+1] + B[l-2])   (out-of-range -> 0)
// LDS rows: A at rows 0..16 (A[15],A[16] stay 0), B[k] at row 17+(k+2)
// (rows 17,18 stay 0 so B[-1],B[-2] reads are 0). 34 rows x TPB floats.
// addr = row*TPB + t -> bank = t mod 32 for every access: 2-way, free.
// Each thread touches only its own column t -> NO barriers needed.

__global__ __launch_bounds__(TPB) void quant_main_kernel(
    const float* __restrict__ weight,
    const float* __restrict__ w_min,
    const float* __restrict__ w_max,
    float* __restrict__ dequant,
    _Float16* __restrict__ partial,
    float* __restrict__ out_ent)
{
    __shared__ float bins[34 * TPB];

    const int t  = threadIdx.x;
    const int c  = blockIdx.x * TPB + t;     // column (coalesced)
    const int r0 = blockIdx.y * RPB;

    // zero the entropy accumulator once (stream-ordered before reduce kernel)
    if (blockIdx.x == 0 && blockIdx.y == 0 && t == 0) out_ent[0] = 0.0f;

#pragma unroll
    for (int l = 0; l < 34; ++l) bins[l * TPB + t] = 0.0f;

    const float wmin = w_min[c];
    const float wmax = w_max[c];
    const float mn   = fminf(wmin, wmax - EPS);       // w_min_c
    const float mx   = fmaxf(wmax, mn + EPS);         // w_max_c
    const float rng  = mx - mn;
    const float inv_rng = __builtin_amdgcn_rcpf(rng + EPS);

    const float S     = (TEMP / 15.0f) * LOG2E;       // level spacing, exp2 units
    const float invS  = 15.0f / (TEMP * LOG2E);
    const float scale = inv_rng * (TEMP * LOG2E);     // z = (w-mn)*scale
    const float zb    = -mn * scale;
    const float rng15 = rng * (1.0f / 15.0f);

    const float* __restrict__ wp = weight  + (size_t)r0 * COLS + c;
    float* __restrict__       dq = dequant + (size_t)r0 * COLS + c;

    for (int r = 0; r < RPB; r += UNROLL) {
        float w[UNROLL];
#pragma unroll
        for (int j = 0; j < UNROLL; ++j)
            w[j] = wp[(size_t)(r + j) * COLS];

#pragma unroll
        for (int j = 0; j < UNROLL; ++j) {
            const float z  = fmaf(w[j], scale, zb);
            float kf = floorf(z * invS);
            kf = fminf(fmaxf(kf, 0.0f), 14.0f);       // z in (0,15S) by construction
            const int ki = (int)kf;
            const float f = fmaf(-kf, S, z);          // in [0,S)

            const float t_ = __builtin_amdgcn_exp2f(-fabsf(f));        // e_k
            const float u_ = __builtin_amdgcn_exp2f(-fabsf(f - S));    // e_{k+1}
            // boundary flags survive only in the denominator:
            const float e1 = (kf >= 1.0f)  ? RGEO : 0.0f;   // e_{k-1}/t_
            const float e2 = (kf <= 13.0f) ? RGEO : 0.0f;   // e_{k+2}/u_
            const float t1 = t_ * e1;
            const float u2 = u_ * e2;
            const float s  = (t_ + t1) + (u_ + u2);
            const float inv_s = __builtin_amdgcn_rcpf(s);
            // ws = k*s + (u - tl + 2*uh)
            const float ws = fmaf(kf, s, u_) + fmaf(2.0f, u2, -t1);

            dq[(size_t)(r + j) * COLS] = fmaf(ws * inv_s, rng15, mn);

            const int base = ki * TPB + t;
            bins[base           ] += t_ * inv_s;      // A[k]
            bins[base + 19 * TPB] += u_ * inv_s;      // B[k] at row 17+(k+2)
        }
    }

    // flush: combine gather terms once, write fp16 partials
    float a[17], b[17];
#pragma unroll
    for (int l = 0; l < 17; ++l) a[l] = bins[l * TPB + t];
#pragma unroll
    for (int l = 0; l < 17; ++l) b[l] = bins[(17 + l) * TPB + t];
    // b[j] holds B[j-2]  (rows 17,18 are the zero pads)

    half8_t v0, v1;
#pragma unroll
    for (int l = 0; l < 16; ++l) {
        // bin[l] = A[l] + B[l-1] + RGEO*(A[l+1] + B[l-2])
        const float bin = (a[l] + b[l + 1]) + RGEO * (a[l + 1] + b[l]);
        if (l < 8) v0[l] = (_Float16)bin; else v1[l - 8] = (_Float16)bin;
    }
    half8_t* pp = (half8_t*)(partial + ((size_t)blockIdx.y * COLS + c) * NLEV);
    pp[0] = v0;
    pp[1] = v1;
}

// fused reduce + entropy: one thread per (col, level-pair) = 16384 threads.
// 8 consecutive lanes own one column -> shuffle for the column total.
__global__ __launch_bounds__(256) void reduce_entropy_kernel(
    const _Float16* __restrict__ partial,
    float* __restrict__ out_ent)
{
    __shared__ float red[256];
    const int i = blockIdx.x * 256 + threadIdx.x;    // [0, COLS*NLEV/2)
    const half2_t* p2 = (const half2_t*)partial;

    float m0 = 0.0f, m1 = 0.0f;
#pragma unroll 4
    for (int rb = 0; rb < RBLKS; ++rb) {
        const half2_t v = p2[(size_t)rb * (COLS * NLEV / 2) + i];
        m0 += (float)v[0];
        m1 += (float)v[1];
    }

    float tot = m0 + m1;
    tot += __shfl_xor(tot, 1);
    tot += __shfl_xor(tot, 2);
    tot += __shfl_xor(tot, 4);          // column total across the 8-lane group
    const float inv = __builtin_amdgcn_rcpf(tot + EPS);

    const float p0 = m0 * inv;
    const float p1 = m1 * inv;
    float ent = -(p0 * __logf(p0 + EPS) + p1 * __logf(p1 + EPS));

    red[threadIdx.x] = ent;
    __syncthreads();
#pragma unroll
    for (int off = 128; off > 0; off >>= 1) {
        if (threadIdx.x < off) red[threadIdx.x] += red[threadIdx.x + off];
        __syncthreads();
    }
    if (threadIdx.x == 0) atomicAdd(out_ent, red[0]);   // 64 atomics total
}

extern "C" void kernel_launch(void* const* d_in, const int* in_sizes, int n_in,
                              void* d_out, int out_size, void* d_ws, size_t ws_size,
                              hipStream_t stream)
{
    const float* weight = (const float*)d_in[0];
    const float* w_min  = (const float*)d_in[1];
    const float* w_max  = (const float*)d_in[2];

    float* out     = (float*)d_out;
    float* dequant = out;                          // ROWS*COLS floats
    float* out_ent = out + (size_t)ROWS * COLS;    // 1 float
    _Float16* partial = (_Float16*)d_ws;           // RBLKS*COLS*NLEV halves

    quant_main_kernel<<<dim3(COLS / TPB, RBLKS), TPB, 0, stream>>>(
        weight, w_min, w_max, dequant, partial, out_ent);

    reduce_entropy_kernel<<<(COLS * NLEV / 2) / 256, 256, 0, stream>>>(
        partial, out_ent);
}